// Round 4
// baseline (193.312 us; speedup 1.0000x reference)
//
#include <hip/hip_runtime.h>
#include <hip/hip_bf16.h>
#include <math.h>

// Problem constants (from reference)
constexpr int B = 8;
constexpr int S = 2048;
constexpr int D = 512;
constexpr int P = 64;
constexpr float SCALE = 0.125f;  // 1/sqrt(P)

typedef short bf16x8 __attribute__((ext_vector_type(8)));
typedef float f32x4 __attribute__((ext_vector_type(4)));
typedef unsigned int u32;

__device__ __forceinline__ unsigned short f2bf(float x) {
  __hip_bfloat16 h = __float2bfloat16(x);
  return __builtin_bit_cast(unsigned short, h);
}
__device__ __forceinline__ float bf2f(unsigned short u) {
  unsigned int v = (unsigned int)u << 16;
  return __builtin_bit_cast(float, v);
}

// ---------------------------------------------------------------------------
// Kernel 0: weight prep (fp32 -> bf16, transposed for MFMA B-fragments).
//   WcatT[192][512]: row n = output column (0-63 q / 64-127 k / 128-191 v)
//   WoT  [512][64] : WoT[n*64+k] = Wo[k*512+n]
// ---------------------------------------------------------------------------
__global__ __launch_bounds__(256) void prep_w(
    const float* __restrict__ Wq, const float* __restrict__ Wk,
    const float* __restrict__ Wv, const float* __restrict__ Wo,
    unsigned short* __restrict__ WcatT, unsigned short* __restrict__ WoT) {
  const int i = blockIdx.x * 256 + threadIdx.x;
  if (i < 192 * 512) {
    const int n = i >> 9, k = i & 511;
    const float* W = (n < 64) ? Wq : (n < 128) ? Wk : Wv;
    WcatT[i] = f2bf(W[k * 64 + (n & 63)]);
  }
  if (i < 512 * 64) {
    WoT[i] = f2bf(Wo[(i & 63) * 512 + (i >> 6)]);
  }
}

// ---------------------------------------------------------------------------
// Kernel 1: QKV projection, barrier-free K-loop.
//   C[16384 x 192] = bf16(query) @ WcatT^T, + bias -> q(scaled)/k/vT bf16.
// Grid 512 x 256 thr: block = 32 rows x 192 cols (wave owns 48 cols).
// A-tile (32x512 bf16 = 32 KB) converted once in LDS (XOR-swizzled chunks,
// 2-way max aliasing = free).  B-fragments are read DIRECTLY from global
// (WcatT = 192 KB, L2-resident, shared by all 512 blocks) so the K-loop has
// NO barriers -> no vmcnt(0) drain stalls; 2 blocks/CU overlap freely.
// ---------------------------------------------------------------------------
__global__ __launch_bounds__(256, 2) void qkv_mfma(
    const float* __restrict__ query, const unsigned short* __restrict__ WcatT,
    const float* __restrict__ bq, const float* __restrict__ bk,
    const float* __restrict__ bv, unsigned short* __restrict__ q_bf,
    unsigned short* __restrict__ k_bf, unsigned short* __restrict__ vT_bf) {
  __shared__ __align__(16) unsigned short Aq[32 * 512];  // 32 KB, swizzled

  const int tid = threadIdx.x;
  const int w = tid >> 6;
  const int l = tid & 63;
  const int l15 = l & 15;
  const int l4 = l >> 4;
  const int s0 = blockIdx.x * 32;

  // ---- Prologue: 32 query rows fp32 -> bf16 swizzled LDS A-tile.
  const float* qsrc = query + (size_t)s0 * D;
  for (int step = 0; step < 8; ++step) {
    const int row = step * 4 + w;  // wave-uniform
    const float* pf = qsrc + row * D + l * 8;
    const float4 x = *(const float4*)pf;
    const float4 y = *(const float4*)(pf + 4);
    bf16x8 u;
    u[0] = (short)f2bf(x.x); u[1] = (short)f2bf(x.y);
    u[2] = (short)f2bf(x.z); u[3] = (short)f2bf(x.w);
    u[4] = (short)f2bf(y.x); u[5] = (short)f2bf(y.y);
    u[6] = (short)f2bf(y.z); u[7] = (short)f2bf(y.w);
    *(bf16x8*)&Aq[row * 512 + ((l ^ (row & 7)) << 3)] = u;
  }
  __syncthreads();  // the ONLY barrier

  f32x4 acc[2][3];
#pragma unroll
  for (int st = 0; st < 2; ++st)
#pragma unroll
    for (int nt = 0; nt < 3; ++nt) acc[st][nt] = (f32x4){0.f, 0.f, 0.f, 0.f};

  const int wn = w * 48;  // wave's first output column

#pragma unroll
  for (int kc = 0; kc < 8; ++kc) {
#pragma unroll
    for (int kk = 0; kk < 2; ++kk) {
      bf16x8 bfr[3];
#pragma unroll
      for (int nt = 0; nt < 3; ++nt) {
        const int n = wn + nt * 16 + l15;
        bfr[nt] = *(const bf16x8*)(WcatT + (size_t)n * 512 + kc * 64 +
                                   kk * 32 + l4 * 8);
      }
      bf16x8 af[2];
#pragma unroll
      for (int st = 0; st < 2; ++st) {
        const int row = st * 16 + l15;
        const int slot = (kc * 8 + kk * 4 + l4) ^ (row & 7);
        af[st] = *(const bf16x8*)&Aq[row * 512 + (slot << 3)];
      }
#pragma unroll
      for (int st = 0; st < 2; ++st)
#pragma unroll
        for (int nt = 0; nt < 3; ++nt)
          acc[st][nt] = __builtin_amdgcn_mfma_f32_16x16x32_bf16(
              af[st], bfr[nt], acc[st][nt], 0, 0, 0);
    }
  }

  // ---- Epilogue: bias, split into q (scaled) / k / vT.
  const int batch = s0 >> 11;
  const int sloc = s0 & 2047;
#pragma unroll
  for (int st = 0; st < 2; ++st) {
#pragma unroll
    for (int nt = 0; nt < 3; ++nt) {
      const int col = wn + nt * 16 + l15;
      const int mat = col >> 6;   // uniform per tile
      const int p = col & 63;
      const float bb = ((mat == 0) ? bq : (mat == 1) ? bk : bv)[p];
#pragma unroll
      for (int r = 0; r < 4; ++r) {
        const int row = st * 16 + l4 * 4 + r;
        const float vl = acc[st][nt][r] + bb;
        if (mat == 0)
          q_bf[(size_t)(s0 + row) * P + p] = f2bf(vl * SCALE);
        else if (mat == 1)
          k_bf[(size_t)(s0 + row) * P + p] = f2bf(vl);
        else
          vT_bf[((size_t)batch * P + p) * S + sloc + row] = f2bf(vl);
      }
    }
  }
}

// ---------------------------------------------------------------------------
// Kernel 2: flash attention + fused output projection.
// Grid 1024 x 256 thr: block = 16 q-rows of one batch (blk&7 = batch -> XCD
// L2 locality); 4 waves split t (512 each, 16 windows of 32).
// Software pipeline: k-frags for window w+1 and v-frags for window w are
// issued before the exp chain, giving each load a full window of cover.
// LDS ~24 KB + <=128 VGPR -> 4 blocks/CU = 4 waves/SIMD (vs 2 last round).
// Epilogue: combine wave partials, normalize -> bf16, then out = wnorm @ WoT
// + bo via MFMA (WoT B-frags straight from L2; all blocks share 64 KB).
// ---------------------------------------------------------------------------
__global__ __launch_bounds__(256, 4) void attn_fused(
    const unsigned short* __restrict__ q_bf,
    const unsigned short* __restrict__ k_bf,
    const unsigned short* __restrict__ vT_bf,
    const unsigned short* __restrict__ WoT, const float* __restrict__ bo,
    float* __restrict__ out) {
  __shared__ __align__(16) unsigned short e_lds[4][16 * 32];  // 4 KB
  __shared__ __align__(16) float wacc[4][16 * 64];            // 16 KB
  __shared__ float l_lds[4][16];                              // 256 B
  __shared__ __align__(16) unsigned short wnorm[16 * 72];     // 2.25 KB (pad)

  const int tid = threadIdx.x;
  const int w = tid >> 6;
  const int lane = tid & 63;
  const int l15 = lane & 15;
  const int l4 = lane >> 4;

  const int blk = blockIdx.x;
  const int b = blk & 7;        // batch -> XCD (perf heuristic only)
  const int s0q = (blk >> 3) * 16;

  const unsigned short* qb = q_bf + ((size_t)b * S + s0q) * P;
  const unsigned short* kb = k_bf + (size_t)b * S * P;
  const unsigned short* vtb = vT_bf + (size_t)b * P * S;

  // q A-fragments (rows l15, k halves)
  bf16x8 aq[2];
#pragma unroll
  for (int h = 0; h < 2; ++h)
    aq[h] = *(const bf16x8*)(qb + (size_t)l15 * P + h * 32 + l4 * 8);

  f32x4 acc[4];
#pragma unroll
  for (int pc = 0; pc < 4; ++pc) acc[pc] = (f32x4){0.f, 0.f, 0.f, 0.f};
  float lpart[4] = {0.f, 0.f, 0.f, 0.f};

  const int t0w = w * 512;

  // Preload k-frags for window 0.
  bf16x8 bk_c[2][2];
#pragma unroll
  for (int tile = 0; tile < 2; ++tile)
#pragma unroll
    for (int h = 0; h < 2; ++h)
      bk_c[tile][h] = *(const bf16x8*)(kb + (size_t)(t0w + tile * 16 + l15) * P +
                                       h * 32 + l4 * 8);

  for (int win = 0; win < 16; ++win) {
    const int t0 = t0w + win * 32;
    const int t0n = t0w + ((win + 1) & 15) * 32;  // wrap: avoids OOB, no branch

    // v-frags for CURRENT window (consumed after exp -> latency covered)
    bf16x8 bv_c[4];
#pragma unroll
    for (int pc = 0; pc < 4; ++pc)
      bv_c[pc] = *(const bf16x8*)(vtb + (size_t)(pc * 16 + l15) * S + t0 +
                                  l4 * 8);
    // k-frags for NEXT window (consumed next iteration)
    bf16x8 bk_n[2][2];
#pragma unroll
    for (int tile = 0; tile < 2; ++tile)
#pragma unroll
      for (int h = 0; h < 2; ++h)
        bk_n[tile][h] = *(const bf16x8*)(kb +
                                         (size_t)(t0n + tile * 16 + l15) * P +
                                         h * 32 + l4 * 8);

    // QK^T -> exp -> bf16 e-tile.  Chunk-XOR store: row rr keeps its 16B
    // chunk c at physical slot c^(rr&3)  (write conflicts 8-way -> 4-way).
#pragma unroll
    for (int tile = 0; tile < 2; ++tile) {
      f32x4 c = (f32x4){0.f, 0.f, 0.f, 0.f};
      c = __builtin_amdgcn_mfma_f32_16x16x32_bf16(aq[0], bk_c[tile][0], c, 0,
                                                  0, 0);
      c = __builtin_amdgcn_mfma_f32_16x16x32_bf16(aq[1], bk_c[tile][1], c, 0,
                                                  0, 0);
      const int ch = tile * 2 + (l15 >> 3);  // logical 8-elem chunk 0..3
#pragma unroll
      for (int r = 0; r < 4; ++r) {
        const int rr = l4 * 4 + r;
        const unsigned short eu = f2bf(__expf(c[r]));
        lpart[r] += bf2f(eu);
        e_lds[w][rr * 32 + ((ch ^ (rr & 3)) << 3) + (l15 & 7)] = eu;
      }
    }

    // PV: A = e-tile in A-layout (row l15, chunk l4 at physical l4^(l15&3)).
    const bf16x8 ae =
        *(const bf16x8*)&e_lds[w][l15 * 32 + ((l4 ^ (l15 & 3)) << 3)];
#pragma unroll
    for (int pc = 0; pc < 4; ++pc)
      acc[pc] = __builtin_amdgcn_mfma_f32_16x16x32_bf16(ae, bv_c[pc], acc[pc],
                                                        0, 0, 0);

#pragma unroll
    for (int tile = 0; tile < 2; ++tile)
#pragma unroll
      for (int h = 0; h < 2; ++h) bk_c[tile][h] = bk_n[tile][h];
  }

  // Row-sums across the 16 lanes sharing each row group.
#pragma unroll
  for (int r = 0; r < 4; ++r) {
    float v = lpart[r];
    v += __shfl_xor(v, 1, 64);
    v += __shfl_xor(v, 2, 64);
    v += __shfl_xor(v, 4, 64);
    v += __shfl_xor(v, 8, 64);
    if (l15 == 0) l_lds[w][l4 * 4 + r] = v;
  }

  // Stash wave-partial PV (waves cover disjoint t-ranges).
#pragma unroll
  for (int pc = 0; pc < 4; ++pc)
#pragma unroll
    for (int r = 0; r < 4; ++r)
      wacc[w][(l4 * 4 + r) * 64 + pc * 16 + l15] = acc[pc][r];
  __syncthreads();

  // Combine + normalize -> bf16 wnorm[16][64] (stride 72 pads bank pattern).
  {
    const int row = tid >> 4;
    const int p0 = (tid & 15) * 4;
    float4 s = {0.f, 0.f, 0.f, 0.f};
    float ls = 0.f;
#pragma unroll
    for (int ww = 0; ww < 4; ++ww) {
      const float4 t = *(const float4*)&wacc[ww][row * 64 + p0];
      s.x += t.x; s.y += t.y; s.z += t.z; s.w += t.w;
      ls += l_lds[ww][row];
    }
    const float rcp = 1.f / ls;
    const u32 u01 = (u32)f2bf(s.x * rcp) | ((u32)f2bf(s.y * rcp) << 16);
    const u32 u23 = (u32)f2bf(s.z * rcp) | ((u32)f2bf(s.w * rcp) << 16);
    u32* dst = (u32*)&wnorm[row * 72 + p0];
    dst[0] = u01;
    dst[1] = u23;
  }
  __syncthreads();

  // Fused output projection: out[16 x 512] = wnorm @ WoT^T + bo.
  const bf16x8 a0 = *(const bf16x8*)&wnorm[l15 * 72 + l4 * 8];
  const bf16x8 a1 = *(const bf16x8*)&wnorm[l15 * 72 + 32 + l4 * 8];
  const size_t orow0 = (size_t)b * S + s0q;
#pragma unroll
  for (int nt = 0; nt < 8; ++nt) {
    const int col = w * 128 + nt * 16 + l15;
    const bf16x8 b0 = *(const bf16x8*)(WoT + (size_t)col * 64 + l4 * 8);
    const bf16x8 b1 = *(const bf16x8*)(WoT + (size_t)col * 64 + 32 + l4 * 8);
    f32x4 c = (f32x4){0.f, 0.f, 0.f, 0.f};
    c = __builtin_amdgcn_mfma_f32_16x16x32_bf16(a0, b0, c, 0, 0, 0);
    c = __builtin_amdgcn_mfma_f32_16x16x32_bf16(a1, b1, c, 0, 0, 0);
    const float bb = bo[col];
#pragma unroll
    for (int r = 0; r < 4; ++r)
      out[(orow0 + l4 * 4 + r) * D + col] = c[r] + bb;
  }
}

// ---------------------------------------------------------------------------
extern "C" void kernel_launch(void* const* d_in, const int* in_sizes, int n_in,
                              void* d_out, int out_size, void* d_ws,
                              size_t ws_size, hipStream_t stream) {
  const float* query = (const float*)d_in[0];
  // d_in[1] = attention_mask: unused (per-row additive constant -> softmax no-op)
  const float* Wq = (const float*)d_in[2];
  const float* bq = (const float*)d_in[3];
  const float* Wk = (const float*)d_in[4];
  const float* bk = (const float*)d_in[5];
  const float* Wv = (const float*)d_in[6];
  const float* bv = (const float*)d_in[7];
  const float* Wo = (const float*)d_in[8];
  const float* bo = (const float*)d_in[9];
  float* out = (float*)d_out;

  // Workspace (bf16): q 2MB | k 2MB | vT 2MB | WcatT 192KB | WoT 64KB
  const size_t n_rows = (size_t)B * S;   // 16384
  const size_t proj = n_rows * P;        // 1,048,576
  unsigned short* qbf = (unsigned short*)d_ws;
  unsigned short* kbf = qbf + proj;
  unsigned short* vtbf = kbf + proj;
  unsigned short* WcatT = vtbf + proj;
  unsigned short* WoT = WcatT + 192 * 512;

  prep_w<<<384, 256, 0, stream>>>(Wq, Wk, Wv, Wo, WcatT, WoT);
  qkv_mfma<<<512, 256, 0, stream>>>(query, WcatT, bq, bk, bv, qbf, kbf, vtbf);
  attn_fused<<<1024, 256, 0, stream>>>(qbf, kbf, vtbf, WoT, bo, out);
}

// Round 5
// 140.172 us; speedup vs baseline: 1.3791x; 1.3791x over previous
//
#include <hip/hip_runtime.h>
#include <hip/hip_bf16.h>
#include <math.h>

// Problem constants (from reference)
constexpr int B = 8;
constexpr int S = 2048;
constexpr int D = 512;
constexpr int P = 64;
constexpr float SCALE = 0.125f;  // 1/sqrt(P)

typedef short bf16x8 __attribute__((ext_vector_type(8)));
typedef float f32x4 __attribute__((ext_vector_type(4)));
typedef unsigned int u32;

__device__ __forceinline__ unsigned short f2bf(float x) {
  __hip_bfloat16 h = __float2bfloat16(x);
  return __builtin_bit_cast(unsigned short, h);
}
__device__ __forceinline__ float bf2f(unsigned short u) {
  unsigned int v = (unsigned int)u << 16;
  return __builtin_bit_cast(float, v);
}

// Async global->LDS, 16B per lane. LDS dest = wave-uniform base + lane*16.
__device__ __forceinline__ void ld_g2lds16(const unsigned short* g,
                                           unsigned short* l) {
  __builtin_amdgcn_global_load_lds(
      (const __attribute__((address_space(1))) u32*)g,
      (__attribute__((address_space(3))) u32*)l, 16, 0, 0);
}

// ---------------------------------------------------------------------------
// Kernel 0: weight prep (fp32 -> bf16, transposed for MFMA B-fragments).
//   WcatT[192][512]: row n = output column (0-63 q / 64-127 k / 128-191 v)
//   WoT  [512][64] : WoT[n*64+k] = Wo[k*512+n]
// ---------------------------------------------------------------------------
__global__ __launch_bounds__(256) void prep_w(
    const float* __restrict__ Wq, const float* __restrict__ Wk,
    const float* __restrict__ Wv, const float* __restrict__ Wo,
    unsigned short* __restrict__ WcatT, unsigned short* __restrict__ WoT) {
  const int i = blockIdx.x * 256 + threadIdx.x;
  if (i < 192 * 512) {
    const int n = i >> 9, k = i & 511;
    const float* W = (n < 64) ? Wq : (n < 128) ? Wk : Wv;
    WcatT[i] = f2bf(W[k * 64 + (n & 63)]);
  }
  if (i < 512 * 64) {
    WoT[i] = f2bf(Wo[(i & 63) * 512 + (i >> 6)]);
  }
}

// ---------------------------------------------------------------------------
// Kernel 1: QKV projection (v3).  C[16384x192] = bf16(query) @ WcatT^T + bias.
// Grid 512 x 256 thr, 2 blocks/CU (80 KB LDS).  Block = 32 rows x 192 cols;
// wave = 16 rows (rg=w&1) x 96 cols (ch=w>>1, 6 n-tiles).
// A-tile converted fp32->bf16 once (query read exactly once, HBM floor
// 5.3 us).  B staged per 64-K-chunk via global_load_lds into a DOUBLE
// buffer; next chunk issued before computing current -> its L2 latency is
// covered by 12 MFMA/wave of compute; ONE barrier per chunk.
// (Round-4's direct-L2 B-frag reads were 16-line gathers -> L1-transaction
// bound; staging batches them 16x.)
// ---------------------------------------------------------------------------
__global__ __launch_bounds__(256, 2) void qkv_mfma(
    const float* __restrict__ query, const unsigned short* __restrict__ WcatT,
    const float* __restrict__ bq, const float* __restrict__ bk,
    const float* __restrict__ bv, unsigned short* __restrict__ q_bf,
    unsigned short* __restrict__ k_bf, unsigned short* __restrict__ vT_bf) {
  __shared__ __align__(16) unsigned short Aq[32 * 512];     // 32 KB, swizzled
  __shared__ __align__(16) unsigned short Bb[2][192 * 64];  // 48 KB, swizzled

  const int tid = threadIdx.x;
  const int w = tid >> 6;
  const int l = tid & 63;
  const int l15 = l & 15;
  const int l4 = l >> 4;
  const int s0 = blockIdx.x * 32;
  const int rg = w & 1;   // row group (16 rows)
  const int ch = w >> 1;  // col half (96 cols)

  // ---- Prologue A: 32 query rows fp32 -> bf16 swizzled LDS tile.
  const float* qsrc = query + (size_t)s0 * D;
  for (int step = 0; step < 8; ++step) {
    const int row = step * 4 + w;  // wave-uniform
    const float* pf = qsrc + row * D + l * 8;
    const float4 x = *(const float4*)pf;
    const float4 y = *(const float4*)(pf + 4);
    bf16x8 u;
    u[0] = (short)f2bf(x.x); u[1] = (short)f2bf(x.y);
    u[2] = (short)f2bf(x.z); u[3] = (short)f2bf(x.w);
    u[4] = (short)f2bf(y.x); u[5] = (short)f2bf(y.y);
    u[6] = (short)f2bf(y.z); u[7] = (short)f2bf(y.w);
    *(bf16x8*)&Aq[row * 512 + ((l ^ (row & 7)) << 3)] = u;
  }

  // ---- Stage B chunk 0.  Lane l of call c loads row n = c*32+w*8+(l>>3);
  // LDS phys chunk l&7 holds logical chunk (l&7)^(n&7); n&7 == l>>3.
#pragma unroll
  for (int c = 0; c < 6; ++c) {
    const int n = c * 32 + w * 8 + (l >> 3);
    const unsigned short* gp =
        WcatT + (size_t)n * 512 + (((l & 7) ^ (l >> 3)) << 3);
    ld_g2lds16(gp, &Bb[0][(c * 256 + w * 64) * 8]);
  }
  __syncthreads();

  f32x4 acc[6];
#pragma unroll
  for (int nt = 0; nt < 6; ++nt) acc[nt] = (f32x4){0.f, 0.f, 0.f, 0.f};

  for (int kc = 0; kc < 8; ++kc) {
    if (kc < 7) {  // stage NEXT chunk into other buffer (latency covered)
#pragma unroll
      for (int c = 0; c < 6; ++c) {
        const int n = c * 32 + w * 8 + (l >> 3);
        const unsigned short* gp = WcatT + (size_t)n * 512 + (kc + 1) * 64 +
                                   (((l & 7) ^ (l >> 3)) << 3);
        ld_g2lds16(gp, &Bb[(kc + 1) & 1][(c * 256 + w * 64) * 8]);
      }
    }
    const unsigned short* Bcur = &Bb[kc & 1][0];
#pragma unroll
    for (int kk = 0; kk < 2; ++kk) {
      const int row = rg * 16 + l15;
      const int aslot = (kc * 8 + kk * 4 + l4) ^ (row & 7);
      const bf16x8 af = *(const bf16x8*)&Aq[row * 512 + (aslot << 3)];
      bf16x8 bfr[6];
#pragma unroll
      for (int nt = 0; nt < 6; ++nt) {
        const int n = ch * 96 + nt * 16 + l15;
        const int slot = (kk * 4 + l4) ^ (n & 7);
        bfr[nt] = *(const bf16x8*)&Bcur[n * 64 + (slot << 3)];
      }
#pragma unroll
      for (int nt = 0; nt < 6; ++nt)
        acc[nt] = __builtin_amdgcn_mfma_f32_16x16x32_bf16(af, bfr[nt], acc[nt],
                                                          0, 0, 0);
    }
    __syncthreads();  // next-chunk stage complete + this chunk's reads done
  }

  // ---- Epilogue: bias, split into q (scaled) / k / vT.
  const int batch = s0 >> 11;
  const int sloc = s0 & 2047;
#pragma unroll
  for (int nt = 0; nt < 6; ++nt) {
    const int col = ch * 96 + nt * 16 + l15;
    const int mat = col >> 6;  // uniform per tile (16-col tiles, 64-bounds)
    const int p = col & 63;
    const float bb = ((mat == 0) ? bq : (mat == 1) ? bk : bv)[p];
#pragma unroll
    for (int r = 0; r < 4; ++r) {
      const int row = rg * 16 + l4 * 4 + r;
      const float vl = acc[nt][r] + bb;
      if (mat == 0)
        q_bf[(size_t)(s0 + row) * P + p] = f2bf(vl * SCALE);
      else if (mat == 1)
        k_bf[(size_t)(s0 + row) * P + p] = f2bf(vl);
      else
        vT_bf[((size_t)batch * P + p) * S + sloc + row] = f2bf(vl);
    }
  }
}

// ---------------------------------------------------------------------------
// Kernel 2: flash attention + fused output projection (v5).
// Grid 256 x 512 thr (8 waves, 2/SIMD; 145 KB LDS -> 1 block/CU).
// Block = 64 q-rows of one batch (blk&7 = batch -> XCD L2 pinning).
// Wave split: qg = w&1 (32 rows, 2 subtiles), th = w>>1 (512-t quarter,
// 8 windows of 64 t).  k/v windows staged cooperatively into DOUBLE-buffered
// LDS (kv traffic amortized over 64 q-rows: 128 MB L2 total, 4x less than
// round 4); next window staged before computing current -> one barrier per
// window, stage latency covered by 8 waves x 32 MFMA of compute.
// Epilogue: t-partial combine via LDS (aliased onto k-buffers), normalize,
// out = wnorm @ WoT + bo (wave = 16 rows x 256 cols).
// ---------------------------------------------------------------------------
__global__ __launch_bounds__(512, 2) void attn_fused(
    const unsigned short* __restrict__ q_bf,
    const unsigned short* __restrict__ k_bf,
    const unsigned short* __restrict__ vT_bf,
    const unsigned short* __restrict__ WoT, const float* __restrict__ bo,
    float* __restrict__ out) {
  __shared__ __align__(16) unsigned short kb[2][4][64 * 64];  // 64 KB [buf][th]
  __shared__ __align__(16) unsigned short vb[2][4][64 * 64];  // 64 KB
  __shared__ __align__(16) unsigned short e_s[8][16 * 64];    // 16 KB per-wave
  __shared__ float l_s[8][32];                                // 1 KB

  const int tid = threadIdx.x;
  const int w = tid >> 6;
  const int lane = tid & 63;
  const int l15 = lane & 15;
  const int l4 = lane >> 4;
  const int qg = w & 1;   // q group: rows s0 + qg*32
  const int th = w >> 1;  // t quarter: t in [th*512, th*512+512)

  const int blk = blockIdx.x;
  const int b = blk & 7;
  const int s0 = (blk >> 3) * 64;

  const unsigned short* qb = q_bf + ((size_t)b * S + s0) * P;
  const unsigned short* kbg = k_bf + (size_t)b * S * P;
  const unsigned short* vtg = vT_bf + (size_t)b * P * S;

  // q A-fragments for this wave's 32 rows (2 subtiles).
  bf16x8 aq[2][2];
#pragma unroll
  for (int st = 0; st < 2; ++st)
#pragma unroll
    for (int h = 0; h < 2; ++h)
      aq[st][h] = *(const bf16x8*)(qb + (size_t)(qg * 32 + st * 16 + l15) * P +
                                   h * 32 + l4 * 8);

  f32x4 acc[2][4];
#pragma unroll
  for (int st = 0; st < 2; ++st)
#pragma unroll
    for (int pc = 0; pc < 4; ++pc) acc[st][pc] = (f32x4){0.f, 0.f, 0.f, 0.f};
  float lpart[2][4] = {{0.f, 0.f, 0.f, 0.f}, {0.f, 0.f, 0.f, 0.f}};

  // Staging role: wave (th, qg): qg==0 stages k for quarter th, qg==1 stages v.
  // Each tile is 8 KB = 8 issues x (64 lanes x 16 B).
  const int jrow = (lane >> 3);      // 0..7
  const int jch = lane & 7;          // 16B chunk within 128B row
  // Stage window 0 for all quarters.
  {
    const int t0 = th * 512;
#pragma unroll
    for (int j = 0; j < 8; ++j) {
      if (qg == 0) {
        const unsigned short* gp =
            kbg + ((size_t)t0 + j * 8 + jrow) * P + jch * 8;
        ld_g2lds16(gp, &kb[0][th][j * 512]);
      } else {
        const unsigned short* gp =
            vtg + ((size_t)(j * 8 + jrow)) * S + t0 + jch * 8;
        ld_g2lds16(gp, &vb[0][th][j * 512]);
      }
    }
  }
  __syncthreads();

  for (int win = 0; win < 8; ++win) {
    if (win < 7) {  // stage next window into the other buffer
      const int t0n = th * 512 + (win + 1) * 64;
      const int nb = (win + 1) & 1;
#pragma unroll
      for (int j = 0; j < 8; ++j) {
        if (qg == 0) {
          const unsigned short* gp =
              kbg + ((size_t)t0n + j * 8 + jrow) * P + jch * 8;
          ld_g2lds16(gp, &kb[nb][th][j * 512]);
        } else {
          const unsigned short* gp =
              vtg + ((size_t)(j * 8 + jrow)) * S + t0n + jch * 8;
          ld_g2lds16(gp, &vb[nb][th][j * 512]);
        }
      }
    }

    const unsigned short* kt = &kb[win & 1][th][0];
    const unsigned short* vt = &vb[win & 1][th][0];

    // Hoisted fragment loads (shared by both subtiles).
    bf16x8 bkf[4][2], bvf[4][2];
#pragma unroll
    for (int nt = 0; nt < 4; ++nt)
#pragma unroll
      for (int h = 0; h < 2; ++h)
        bkf[nt][h] =
            *(const bf16x8*)&kt[(nt * 16 + l15) * 64 + h * 32 + l4 * 8];
#pragma unroll
    for (int pc = 0; pc < 4; ++pc)
#pragma unroll
      for (int kk = 0; kk < 2; ++kk)
        bvf[pc][kk] =
            *(const bf16x8*)&vt[(pc * 16 + l15) * 64 + kk * 32 + l4 * 8];

#pragma unroll
    for (int st = 0; st < 2; ++st) {
      // QK^T: 16 rows x 64 t
      f32x4 sc[4];
#pragma unroll
      for (int nt = 0; nt < 4; ++nt) {
        f32x4 c = (f32x4){0.f, 0.f, 0.f, 0.f};
        c = __builtin_amdgcn_mfma_f32_16x16x32_bf16(aq[st][0], bkf[nt][0], c,
                                                    0, 0, 0);
        sc[nt] = __builtin_amdgcn_mfma_f32_16x16x32_bf16(aq[st][1], bkf[nt][1],
                                                         c, 0, 0, 0);
      }
      // exp -> bf16 e-tile (chunk-XOR swizzled row-major [16][64])
#pragma unroll
      for (int nt = 0; nt < 4; ++nt) {
        const int ch = nt * 2 + (l15 >> 3);  // logical 8-elem chunk 0..7
#pragma unroll
        for (int r = 0; r < 4; ++r) {
          const int rr = l4 * 4 + r;
          const unsigned short eu = f2bf(__expf(sc[nt][r]));
          lpart[st][r] += bf2f(eu);
          e_s[w][rr * 64 + ((ch ^ (rr & 7)) << 3) + (l15 & 7)] = eu;
        }
      }
      // PV: A = e-tile (A-layout b128 reads), B = v fragments
      bf16x8 ae[2];
#pragma unroll
      for (int kk = 0; kk < 2; ++kk)
        ae[kk] = *(const bf16x8*)&e_s[w][l15 * 64 +
                                         (((kk * 4 + l4) ^ (l15 & 7)) << 3)];
#pragma unroll
      for (int pc = 0; pc < 4; ++pc) {
        acc[st][pc] = __builtin_amdgcn_mfma_f32_16x16x32_bf16(
            ae[0], bvf[pc][0], acc[st][pc], 0, 0, 0);
        acc[st][pc] = __builtin_amdgcn_mfma_f32_16x16x32_bf16(
            ae[1], bvf[pc][1], acc[st][pc], 0, 0, 0);
      }
    }
    __syncthreads();  // next-window stage complete + this window's reads done
  }

  // ---- Row-sums: butterfly over the 16 col-lanes, publish per-wave partials.
#pragma unroll
  for (int st = 0; st < 2; ++st) {
#pragma unroll
    for (int r = 0; r < 4; ++r) {
      float v = lpart[st][r];
      v += __shfl_xor(v, 1, 64);
      v += __shfl_xor(v, 2, 64);
      v += __shfl_xor(v, 4, 64);
      v += __shfl_xor(v, 8, 64);
      if (l15 == 0) l_s[w][st * 16 + l4 * 4 + r] = v;
    }
  }

  // ---- Combine t-partials.  pacc aliases the (now idle) k/v buffers.
  float* pacc = (float*)&kb[0][0][0];  // [2 qg][3][32][64] f32 = 48 KB
  if (th > 0) {
#pragma unroll
    for (int st = 0; st < 2; ++st)
#pragma unroll
      for (int pc = 0; pc < 4; ++pc)
#pragma unroll
        for (int r = 0; r < 4; ++r)
          pacc[((size_t)(qg * 3 + th - 1) * 32 + st * 16 + l4 * 4 + r) * 64 +
               pc * 16 + l15] = acc[st][pc][r];
  }
  __syncthreads();

  unsigned short* wnorm = &e_s[0][0];  // [2 qg][32][64] bf16 = 8 KB (alias)
  if (th == 0) {
#pragma unroll
    for (int st = 0; st < 2; ++st) {
      float rl[4];
#pragma unroll
      for (int r = 0; r < 4; ++r) {
        const int row = st * 16 + l4 * 4 + r;
        rl[r] = 1.f / (l_s[qg][row] + l_s[2 + qg][row] + l_s[4 + qg][row] +
                       l_s[6 + qg][row]);
      }
#pragma unroll
      for (int pc = 0; pc < 4; ++pc)
#pragma unroll
        for (int r = 0; r < 4; ++r) {
          float s = acc[st][pc][r];
#pragma unroll
          for (int j = 0; j < 3; ++j)
            s += pacc[((size_t)(qg * 3 + j) * 32 + st * 16 + l4 * 4 + r) * 64 +
                      pc * 16 + l15];
          wnorm[(qg * 32 + st * 16 + l4 * 4 + r) * 64 + pc * 16 + l15] =
              f2bf(s * rl[r]);
        }
    }
  }
  __syncthreads();

  // ---- Fused output projection: wave = 16 rows x 256 cols.
  const int sub = w & 3;      // row subtile (16 rows)
  const int chalf = w >> 2;   // col half (256 cols)
  const int qgs = sub >> 1;
  const int lrow = (sub & 1) * 16 + l15;
  const bf16x8 a0 = *(const bf16x8*)&wnorm[(qgs * 32 + lrow) * 64 + l4 * 8];
  const bf16x8 a1 =
      *(const bf16x8*)&wnorm[(qgs * 32 + lrow) * 64 + 32 + l4 * 8];
  const size_t orow0 = (size_t)b * S + s0 + sub * 16;
#pragma unroll
  for (int ct = 0; ct < 16; ++ct) {
    const int col = chalf * 256 + ct * 16 + l15;
    const bf16x8 b0 = *(const bf16x8*)(WoT + (size_t)col * 64 + l4 * 8);
    const bf16x8 b1 = *(const bf16x8*)(WoT + (size_t)col * 64 + 32 + l4 * 8);
    f32x4 c = (f32x4){0.f, 0.f, 0.f, 0.f};
    c = __builtin_amdgcn_mfma_f32_16x16x32_bf16(a0, b0, c, 0, 0, 0);
    c = __builtin_amdgcn_mfma_f32_16x16x32_bf16(a1, b1, c, 0, 0, 0);
    const float bb = bo[col];
#pragma unroll
    for (int r = 0; r < 4; ++r)
      out[(orow0 + l4 * 4 + r) * D + col] = c[r] + bb;
  }
}

// ---------------------------------------------------------------------------
extern "C" void kernel_launch(void* const* d_in, const int* in_sizes, int n_in,
                              void* d_out, int out_size, void* d_ws,
                              size_t ws_size, hipStream_t stream) {
  const float* query = (const float*)d_in[0];
  // d_in[1] = attention_mask: unused (per-row additive constant -> softmax no-op)
  const float* Wq = (const float*)d_in[2];
  const float* bq = (const float*)d_in[3];
  const float* Wk = (const float*)d_in[4];
  const float* bk = (const float*)d_in[5];
  const float* Wv = (const float*)d_in[6];
  const float* bv = (const float*)d_in[7];
  const float* Wo = (const float*)d_in[8];
  const float* bo = (const float*)d_in[9];
  float* out = (float*)d_out;

  // Workspace (bf16): q 2MB | k 2MB | vT 2MB | WcatT 192KB | WoT 64KB
  const size_t n_rows = (size_t)B * S;   // 16384
  const size_t proj = n_rows * P;        // 1,048,576
  unsigned short* qbf = (unsigned short*)d_ws;
  unsigned short* kbf = qbf + proj;
  unsigned short* vtbf = kbf + proj;
  unsigned short* WcatT = vtbf + proj;
  unsigned short* WoT = WcatT + 192 * 512;

  prep_w<<<384, 256, 0, stream>>>(Wq, Wk, Wv, Wo, WcatT, WoT);
  qkv_mfma<<<512, 256, 0, stream>>>(query, WcatT, bq, bk, bv, qbf, kbf, vtbf);
  attn_fused<<<256, 512, 0, stream>>>(qbf, kbf, vtbf, WoT, bo, out);
}